// Round 8
// baseline (496.631 us; speedup 1.0000x reference)
//
#include <hip/hip_runtime.h>
#include <math.h>

#define NBATCH 2048

typedef unsigned short ushortT;
typedef __attribute__((ext_vector_type(8))) short bf16x8;
typedef __attribute__((ext_vector_type(4))) float f32x4;

__device__ __forceinline__ ushortT f2bf(float f) {
  union { float f; unsigned u; } v; v.f = f;
  unsigned r = v.u + 0x7FFF + ((v.u >> 16) & 1);
  return (ushortT)(r >> 16);
}
__device__ __forceinline__ float bf2f(ushortT h) {
  union { float f; unsigned u; } v; v.u = ((unsigned)h) << 16; return v.f;
}

// ws ushort layout:
//   w2t_hi [0,18432)  w2t_lo [18432,36864)           [tap][co][ci]
//   w3t_hi [36864,73728) w3t_lo [73728,110592)       [tap][co][ci]
//   wd1t_hi [110592,311296) wd1t_lo [311296,512000)  [co][ci]
//   s3 bf16 [512000, 512000+2048*3136)               [img][op*64+co]
//   w1t_hi [6934528,+1024) w1t_lo [6935552,+1024)    [n][k32] (9 taps + 23 zero)
//   counter (int) @ushort 6936576
#define WD1T_HI 110592
#define WD1T_LO 311296
#define S3_OFF  512000
#define W1T_HI  6934528
#define W1T_LO  6935552
#define CNT_OFF 6936576

// grid 266: blk 0..48 wd1-transpose tiles; 49..120 w2t; 121..264 w3t; 265 w1t+cnt
__global__ __launch_bounds__(256) void prep_w(const float* __restrict__ w1,
                                              const float* __restrict__ w2,
                                              const float* __restrict__ w3,
                                              const float* __restrict__ wd1,
                                              ushortT* __restrict__ ws) {
  __shared__ float tile[64][65];
  const int blk = blockIdx.x, t = threadIdx.x;
  if (blk < 49) {
    const int ci0 = blk * 64;
    #pragma unroll
    for (int i = 0; i < 16; ++i) {
      int idx = i * 256 + t;
      int ci_l = idx >> 6, co = idx & 63;
      tile[ci_l][co] = wd1[(ci0 + ci_l) * 64 + co];
    }
    __syncthreads();
    const int co = t >> 2, seg = t & 3;
    #pragma unroll
    for (int part = 0; part < 2; ++part) {
      union { ushortT s[8]; bf16x8 v; } uh, ul;
      #pragma unroll
      for (int j = 0; j < 8; ++j) {
        float w = tile[seg * 16 + part * 8 + j][co];
        ushortT hb = f2bf(w);
        uh.s[j] = hb;
        ul.s[j] = f2bf(w - bf2f(hb));
      }
      long o = (long)co * 3136 + ci0 + seg * 16 + part * 8;
      *(bf16x8*)(ws + WD1T_HI + o) = uh.v;
      *(bf16x8*)(ws + WD1T_LO + o) = ul.v;
    }
  } else if (blk < 121) {
    int i = (blk - 49) * 256 + t;                 // [0,18432)
    int tap = i / 2048, r = i - tap * 2048, ci = r >> 6, co = r & 63;
    float w = w2[i];
    ushortT hb = f2bf(w);
    ushortT lb = f2bf(w - bf2f(hb));
    int o = (tap * 64 + co) * 32 + ci;
    ws[o] = hb; ws[18432 + o] = lb;
  } else if (blk < 265) {
    int j = (blk - 121) * 256 + t;                // [0,36864)
    int tap = j >> 12, r = j & 4095, ci = r >> 6, co = r & 63;
    float w = w3[j];
    ushortT hb = f2bf(w);
    ushortT lb = f2bf(w - bf2f(hb));
    int o = (tap * 64 + co) * 64 + ci;
    ws[36864 + o] = hb; ws[73728 + o] = lb;
  } else {
    if (t < 32) {
      int n = t;
      #pragma unroll
      for (int k = 0; k < 32; ++k) {
        float w = (k < 9) ? w1[k * 32 + n] : 0.f;
        ushortT hb = f2bf(w);
        ws[W1T_HI + n * 32 + k] = hb;
        ws[W1T_LO + n * 32 + k] = f2bf(w - bf2f(hb));
      }
    }
    if (t == 0) *(int*)(ws + CNT_OFF) = 0;        // reset tail-block ticket counter
  }
}

// ---- fully-fused: conv1+pool, conv2+pool, conv3 (all MFMA) -> s3 bf16;
//      last 128 blocks (atomic ticket) then run dense1-MFMA + dense2 + softmax.
// smem: s1u [256 rows][40] ushorts @0 (20480B)
//       ab0/ab1 [96 rows][40] ushorts @20480/@28160 (im2row, K=32 in rows padded to 40)
//       (stage2+: s2u [81][72] overlays @20480)
//       xinb [30][31] ushorts @35840
__global__ __launch_bounds__(256, 4) void conv_fused(
    const float* __restrict__ xg, const float* __restrict__ b1g,
    const float* __restrict__ b2g, const float* __restrict__ b3g,
    ushortT* __restrict__ wsu, ushortT* __restrict__ s3g,
    const float* __restrict__ bd1g, const float* __restrict__ wd2g,
    const float* __restrict__ bd2g, float* __restrict__ out)
{
  __shared__ __align__(16) unsigned char smem[37700];
  __shared__ int ticket;
  ushortT* s1u  = (ushortT*)smem;
  ushortT* ab0  = (ushortT*)(smem + 20480);
  ushortT* ab1  = (ushortT*)(smem + 28160);
  ushortT* s2u  = (ushortT*)(smem + 20480);       // overlays ab0/ab1 after stage1
  ushortT* xinb = (ushortT*)(smem + 35840);

  const int t = threadIdx.x, b = blockIdx.x;
  const int lane = t & 63, wid = t >> 6;
  const int ln15 = lane & 15, quad = lane >> 4;

  // phase 0: zero s1u + xinb
  {
    uint4 z = make_uint4(0u, 0u, 0u, 0u);
    uint4* p = (uint4*)s1u;
    for (int i = t; i < 1280; i += 256) p[i] = z;
    unsigned* px = (unsigned*)xinb;
    for (int i = t; i < 465; i += 256) px[i] = 0u;
  }
  __syncthreads();
  // phase 1: load image as bf16
  const float* xb = xg + (long)b * 784;
  for (int i = t; i < 784; i += 256) {
    int y = i / 28, x = i - y * 28;
    xinb[(y + 1) * 31 + (x + 1)] = f2bf(xb[i]);
  }
  __syncthreads();

  // ---- stage 1: conv1 (1->32) via MFMA, im2row chunks (96 rows x stride 40)
  {
    const int ntile = wid & 1, mtg = wid >> 1;
    const int nb = ntile * 16;
    const float bias = b1g[nb + ln15];
    bf16x8 bh1 = *(const bf16x8*)(wsu + W1T_HI + (nb + ln15) * 32 + quad * 8);
    bf16x8 bl1 = *(const bf16x8*)(wsu + W1T_LO + (nb + ln15) * 32 + quad * 8);

    auto build = [&](int c, ushortT* buf) {
      int rows = (c < 8) ? 96 : 16;
      if (t < rows) {
        int gm = c * 96 + t;
        int pp = gm >> 2, q = gm & 3;
        int py = pp / 14, px = pp - py * 14;
        int iy = 2 * py + (q >> 1), ix = 2 * px + (q & 1);
        const ushortT* xr = xinb + iy * 31 + ix;
        unsigned d0 = xr[0]  | ((unsigned)xr[1]  << 16);
        unsigned d1 = xr[2]  | ((unsigned)xr[31] << 16);
        unsigned d2 = xr[32] | ((unsigned)xr[33] << 16);
        unsigned d3 = xr[62] | ((unsigned)xr[63] << 16);
        unsigned d4 = xr[64];
        uint4 z = make_uint4(0u, 0u, 0u, 0u);
        *(uint4*)(buf + t * 40)      = make_uint4(d0, d1, d2, d3);
        *(uint4*)(buf + t * 40 + 8)  = make_uint4(d4, 0u, 0u, 0u);
        *(uint4*)(buf + t * 40 + 16) = z;
        *(uint4*)(buf + t * 40 + 24) = z;
        *(uint4*)(buf + t * 40 + 32) = z;
      }
    };
    auto domfma = [&](int c, ushortT* buf) {
      int cnt = (c < 8) ? 3 : (mtg == 0 ? 1 : 0);
      for (int j = 0; j < cnt; ++j) {
        int ml = (c < 8) ? (mtg * 3 + j) : 0;
        int tile = c * 6 + ml;
        bf16x8 a = *(const bf16x8*)(buf + (ml * 16 + ln15) * 40 + quad * 8);
        f32x4 acc = (f32x4){bias, bias, bias, bias};
        acc = __builtin_amdgcn_mfma_f32_16x16x32_bf16(a, bh1, acc, 0, 0, 0);
        acc = __builtin_amdgcn_mfma_f32_16x16x32_bf16(a, bl1, acc, 0, 0, 0);
        float m = fmaxf(fmaxf(acc[0], acc[1]), fmaxf(acc[2], acc[3]));
        int pp = tile * 4 + quad;
        int py = pp / 14, px = pp - py * 14;
        s1u[((py + 1) * 16 + px + 1) * 40 + nb + ln15] = f2bf(fmaxf(m, 0.f));
      }
    };
    build(0, ab0);
    __syncthreads();
    #pragma unroll 1
    for (int c = 0; c < 9; ++c) {
      ushortT* curb = (c & 1) ? ab1 : ab0;
      domfma(c, curb);
      if (c < 8) build(c + 1, (c & 1) ? ab0 : ab1);
      __syncthreads();
    }
  }
  // zero s2u region (ab buffers dead)
  {
    uint4 z = make_uint4(0u, 0u, 0u, 0u);
    uint4* p = (uint4*)s2u;                        // 5832 ushorts = 729 uint4
    for (int i = t; i < 729; i += 256) p[i] = z;
  }
  __syncthreads();

  // ---- stage 2: conv2 (32->64) MFMA, pool-morton M; prefetched B; pool+relu -> s2u
  {
    const int nth = wid >> 1, mtg = wid & 1;
    const int nmt = mtg ? 6 : 7;
    const int nt0 = nth * 2;
    int abase[7];
    #pragma unroll
    for (int k = 0; k < 7; ++k) {
      int mt = mtg + 2 * k;
      int m = mt * 16 + ln15;
      int pp = m >> 2; if (pp > 48) pp = 48;
      int qq = m & 3;
      int py = pp / 7, px = pp - py * 7;
      int oy = 2 * py + (qq >> 1), ox = 2 * px + (qq & 1);
      abase[k] = (oy * 16 + ox) * 80 + quad * 16;
    }
    const float bia0 = b2g[nt0 * 16 + ln15];
    const float bia1 = b2g[(nt0 + 1) * 16 + ln15];
    f32x4 acc[7][2];
    #pragma unroll
    for (int k = 0; k < 7; ++k) {
      acc[k][0] = (f32x4){bia0, bia0, bia0, bia0};
      acc[k][1] = (f32x4){bia1, bia1, bia1, bia1};
    }
    const char* s1b = (const char*)s1u;
    const ushortT* wbase = wsu + (nt0 * 16 + ln15) * 32 + quad * 8;
    bf16x8 cur[4], nxt[4];
    {
      const ushortT* bp = wbase;
      cur[0] = *(const bf16x8*)bp;
      cur[1] = *(const bf16x8*)(bp + 18432);
      cur[2] = *(const bf16x8*)(bp + 512);
      cur[3] = *(const bf16x8*)(bp + 18432 + 512);
    }
    #pragma unroll 1
    for (int tap = 0; tap < 9; ++tap) {
      {
        int tn = tap < 8 ? tap + 1 : 8;
        const ushortT* bp = wbase + tn * 2048;
        nxt[0] = *(const bf16x8*)bp;
        nxt[1] = *(const bf16x8*)(bp + 18432);
        nxt[2] = *(const bf16x8*)(bp + 512);
        nxt[3] = *(const bf16x8*)(bp + 18432 + 512);
      }
      int ky = tap / 3, kx = tap - (tap / 3) * 3;
      int soff = (ky * 16 + kx) * 80;
      #pragma unroll
      for (int k = 0; k < 7; ++k) {
        if (k < nmt) {
          bf16x8 a = *(const bf16x8*)(s1b + abase[k] + soff);
          acc[k][0] = __builtin_amdgcn_mfma_f32_16x16x32_bf16(a, cur[0], acc[k][0], 0, 0, 0);
          acc[k][0] = __builtin_amdgcn_mfma_f32_16x16x32_bf16(a, cur[1], acc[k][0], 0, 0, 0);
          acc[k][1] = __builtin_amdgcn_mfma_f32_16x16x32_bf16(a, cur[2], acc[k][1], 0, 0, 0);
          acc[k][1] = __builtin_amdgcn_mfma_f32_16x16x32_bf16(a, cur[3], acc[k][1], 0, 0, 0);
        }
      }
      #pragma unroll
      for (int i = 0; i < 4; ++i) cur[i] = nxt[i];
    }
    #pragma unroll
    for (int k = 0; k < 7; ++k) {
      if (k < nmt) {
        int mt = mtg + 2 * k;
        int pp = mt * 4 + quad;
        if (pp < 49) {
          int py = pp / 7, px = pp - py * 7;
          int grow = (py + 1) * 9 + px + 1;
          f32x4 v0 = acc[k][0], v1 = acc[k][1];
          float p0 = fmaxf(fmaxf(v0.x, v0.y), fmaxf(v0.z, v0.w));
          float p1 = fmaxf(fmaxf(v1.x, v1.y), fmaxf(v1.z, v1.w));
          s2u[grow * 72 + nt0 * 16 + ln15]       = f2bf(fmaxf(p0, 0.f));
          s2u[grow * 72 + (nt0 + 1) * 16 + ln15] = f2bf(fmaxf(p1, 0.f));
        }
      }
    }
  }
  __syncthreads();

  // ---- stage 3: conv3 (64->64) MFMA + relu, prefetched B -> s3g bf16
  {
    int abase2[4];
    #pragma unroll
    for (int mt = 0; mt < 4; ++mt) {
      int op = mt * 16 + ln15; if (op > 48) op = 48;
      int oy = op / 7, ox = op - (op / 7) * 7;
      abase2[mt] = (oy * 9 + ox) * 144 + quad * 16;
    }
    const float bia = b3g[wid * 16 + ln15];
    f32x4 acc3[4];
    #pragma unroll
    for (int mt = 0; mt < 4; ++mt) acc3[mt] = (f32x4){bia, bia, bia, bia};
    const char* s2b = (const char*)s2u;
    const ushortT* w3base = wsu + 36864 + (wid * 16 + ln15) * 64 + quad * 8;
    bf16x8 cur[4], nxt[4];
    {
      const ushortT* bp = w3base;
      cur[0] = *(const bf16x8*)bp;
      cur[1] = *(const bf16x8*)(bp + 36864);
      cur[2] = *(const bf16x8*)(bp + 32);
      cur[3] = *(const bf16x8*)(bp + 36864 + 32);
    }
    #pragma unroll 1
    for (int tap = 0; tap < 9; ++tap) {
      {
        int tn = tap < 8 ? tap + 1 : 8;
        const ushortT* bp = w3base + tn * 4096;
        nxt[0] = *(const bf16x8*)bp;
        nxt[1] = *(const bf16x8*)(bp + 36864);
        nxt[2] = *(const bf16x8*)(bp + 32);
        nxt[3] = *(const bf16x8*)(bp + 36864 + 32);
      }
      int ky = tap / 3, kx = tap - (tap / 3) * 3;
      int soff = (ky * 9 + kx) * 144;
      #pragma unroll
      for (int kc = 0; kc < 2; ++kc) {
        #pragma unroll
        for (int mt = 0; mt < 4; ++mt) {
          bf16x8 a = *(const bf16x8*)(s2b + abase2[mt] + soff + kc * 64);
          acc3[mt] = __builtin_amdgcn_mfma_f32_16x16x32_bf16(a, cur[kc * 2],     acc3[mt], 0, 0, 0);
          acc3[mt] = __builtin_amdgcn_mfma_f32_16x16x32_bf16(a, cur[kc * 2 + 1], acc3[mt], 0, 0, 0);
        }
      }
      #pragma unroll
      for (int i = 0; i < 4; ++i) cur[i] = nxt[i];
    }
    ushortT* dst = s3g + (long)b * 3136 + wid * 16 + ln15;
    #pragma unroll
    for (int mt = 0; mt < 4; ++mt)
      #pragma unroll
      for (int r = 0; r < 4; ++r) {
        int op = mt * 16 + quad * 4 + r;
        if (op < 49) dst[op * 64] = f2bf(fmaxf(acc3[mt][r], 0.f));
      }
  }

  // ---- ticket: last 128 blocks run the dense head (16 images each) ----
  __threadfence();
  __syncthreads();
  int* cnt = (int*)(wsu + CNT_OFF);
  if (t == 0)
    ticket = __hip_atomic_fetch_add(cnt, 1, __ATOMIC_ACQ_REL, __HIP_MEMORY_SCOPE_AGENT);
  __syncthreads();
  const int tk = ticket;
  if (tk < NBATCH - 128) return;

  if (t == 0) {
    while (__hip_atomic_load(cnt, __ATOMIC_ACQUIRE, __HIP_MEMORY_SCOPE_AGENT) < NBATCH)
      __builtin_amdgcn_s_sleep(8);
    __threadfence();
  }
  __syncthreads();

  // dense1: C[16 images x 64 ch]; wave wid = 16-ch n-tile, full K (98 chunks)
  float* hvf = (float*)smem;            // [16][64]
  float* lgf = (float*)(smem + 4096);   // lg [16][12] + le [16][12]
  {
    const int m0 = (tk - (NBATCH - 128)) * 16;
    const ushortT* a_p = s3g + (long)(m0 + ln15) * 3136 + quad * 8;
    const ushortT* h_p = wsu + WD1T_HI + (long)(wid * 16 + ln15) * 3136 + quad * 8;
    const ushortT* l_p = wsu + WD1T_LO + (long)(wid * 16 + ln15) * 3136 + quad * 8;
    bf16x8 a  = *(const bf16x8*)a_p;
    bf16x8 wh = *(const bf16x8*)h_p;
    bf16x8 wl = *(const bf16x8*)l_p;
    f32x4 ac0 = (f32x4){0.f, 0.f, 0.f, 0.f};
    f32x4 ac1 = (f32x4){0.f, 0.f, 0.f, 0.f};
    #pragma unroll 2
    for (int i = 1; i < 98; ++i) {
      bf16x8 na = *(const bf16x8*)(a_p + i * 32);
      bf16x8 nh = *(const bf16x8*)(h_p + i * 32);
      bf16x8 nl = *(const bf16x8*)(l_p + i * 32);
      ac0 = __builtin_amdgcn_mfma_f32_16x16x32_bf16(a, wh, ac0, 0, 0, 0);
      ac1 = __builtin_amdgcn_mfma_f32_16x16x32_bf16(a, wl, ac1, 0, 0, 0);
      a = na; wh = nh; wl = nl;
    }
    ac0 = __builtin_amdgcn_mfma_f32_16x16x32_bf16(a, wh, ac0, 0, 0, 0);
    ac1 = __builtin_amdgcn_mfma_f32_16x16x32_bf16(a, wl, ac1, 0, 0, 0);
    const float bias = bd1g[wid * 16 + ln15];
    #pragma unroll
    for (int r = 0; r < 4; ++r)
      hvf[(quad * 4 + r) * 64 + wid * 16 + ln15] = fmaxf(ac0[r] + ac1[r] + bias, 0.f);
    __syncthreads();

    float* lg = lgf;
    float* le = lgf + 192;
    if (t < 160) {
      int im = t / 10, c = t - im * 10;
      float a2 = bd2g[c];
      #pragma unroll
      for (int k = 0; k < 64; ++k) a2 = fmaf(hvf[im * 64 + k], wd2g[k * 10 + c], a2);
      lg[im * 12 + c] = a2;
    }
    __syncthreads();
    if (t < 160) {
      int im = t / 10, c = t - im * 10;
      float m = lg[im * 12];
      #pragma unroll
      for (int i = 1; i < 10; ++i) m = fmaxf(m, lg[im * 12 + i]);
      le[im * 12 + c] = expf(lg[im * 12 + c] - m);
    }
    __syncthreads();
    if (t < 160) {
      int im = t / 10, c = t - im * 10;
      float s = 0.f;
      #pragma unroll
      for (int i = 0; i < 10; ++i) s += le[im * 12 + i];
      out[(long)(m0 + im) * 10 + c] = le[im * 12 + c] / s;
    }
  }
}

extern "C" void kernel_launch(void* const* d_in, const int* in_sizes, int n_in,
                              void* d_out, int out_size, void* d_ws, size_t ws_size,
                              hipStream_t stream) {
  (void)in_sizes; (void)n_in; (void)out_size; (void)ws_size;
  const float* x   = (const float*)d_in[0];
  const float* w1  = (const float*)d_in[1];
  const float* b1  = (const float*)d_in[2];
  const float* w2  = (const float*)d_in[3];
  const float* b2  = (const float*)d_in[4];
  const float* w3  = (const float*)d_in[5];
  const float* b3  = (const float*)d_in[6];
  const float* wd1 = (const float*)d_in[7];
  const float* bd1 = (const float*)d_in[8];
  const float* wd2 = (const float*)d_in[9];
  const float* bd2 = (const float*)d_in[10];
  float* out = (float*)d_out;
  ushortT* wsu = (ushortT*)d_ws;
  ushortT* s3g = wsu + S3_OFF;

  hipLaunchKernelGGL(prep_w, dim3(266), dim3(256), 0, stream, w1, w2, w3, wd1, wsu);
  hipLaunchKernelGGL(conv_fused, dim3(NBATCH), dim3(256), 0, stream,
                     x, b1, b2, b3, wsu, s3g, bd1, wd2, bd2, out);
}

// Round 9
// 164.088 us; speedup vs baseline: 3.0266x; 3.0266x over previous
//
#include <hip/hip_runtime.h>
#include <math.h>

#define NBATCH 2048

typedef unsigned short ushortT;
typedef __attribute__((ext_vector_type(8))) short bf16x8;
typedef __attribute__((ext_vector_type(4))) float f32x4;

__device__ __forceinline__ ushortT f2bf(float f) {
  union { float f; unsigned u; } v; v.f = f;
  unsigned r = v.u + 0x7FFF + ((v.u >> 16) & 1);
  return (ushortT)(r >> 16);
}
__device__ __forceinline__ float bf2f(ushortT h) {
  union { float f; unsigned u; } v; v.u = ((unsigned)h) << 16; return v.f;
}

// ws ushort layout:
//   w2t_hi [0,18432)  w2t_lo [18432,36864)           [tap][co][ci]
//   w3t_hi [36864,73728) w3t_lo [73728,110592)       [tap][co][ci]
//   wd1f_hi [110592,311296) wd1f_lo [311296,512000)  B-frag-major [nt][kk][lane][8]
//   s3 frag-major [512000,+6422528)                  [g][kk][lane-slot][8]
//   w1t_hi [6934528,+1024) w1t_lo [6935552,+1024)    [n][k32] (9 taps + 23 zero)
#define WD1F_HI 110592
#define WD1F_LO 311296
#define S3F_OFF 512000
#define W1T_HI  6934528
#define W1T_LO  6935552

// grid 266: blk 0..48 wd1 frag-major tiles; 49..120 w2t; 121..264 w3t; 265 w1t
__global__ __launch_bounds__(256) void prep_w(const float* __restrict__ w1,
                                              const float* __restrict__ w2,
                                              const float* __restrict__ w3,
                                              const float* __restrict__ wd1,
                                              ushortT* __restrict__ ws) {
  __shared__ float tile[64][65];
  const int blk = blockIdx.x, t = threadIdx.x;
  if (blk < 49) {
    const int ci0 = blk * 64;               // covers kk0 = blk*2, blk*2+1
    #pragma unroll
    for (int i = 0; i < 16; ++i) {
      int idx = i * 256 + t;
      int ci_l = idx >> 6, co = idx & 63;
      tile[ci_l][co] = wd1[(ci0 + ci_l) * 64 + co];
    }
    __syncthreads();
    const int lane = t & 63, kkl = (t >> 6) & 1, nth = t >> 7;
    const int ln15 = lane & 15, quad = lane >> 4;
    const int kk = blk * 2 + kkl;
    #pragma unroll
    for (int ni = 0; ni < 2; ++ni) {
      int nt = nth * 2 + ni;
      union { ushortT s[8]; bf16x8 v; } uh, ul;
      #pragma unroll
      for (int j = 0; j < 8; ++j) {
        float w = tile[kkl * 32 + quad * 8 + j][nt * 16 + ln15];
        ushortT hb = f2bf(w);
        uh.s[j] = hb;
        ul.s[j] = f2bf(w - bf2f(hb));
      }
      long o = ((long)(nt * 98 + kk) * 64 + lane) * 8;
      *(bf16x8*)(ws + WD1F_HI + o) = uh.v;
      *(bf16x8*)(ws + WD1F_LO + o) = ul.v;
    }
  } else if (blk < 121) {
    int i = (blk - 49) * 256 + t;                 // [0,18432)
    int tap = i / 2048, r = i - tap * 2048, ci = r >> 6, co = r & 63;
    float w = w2[i];
    ushortT hb = f2bf(w);
    ushortT lb = f2bf(w - bf2f(hb));
    int o = (tap * 64 + co) * 32 + ci;
    ws[o] = hb; ws[18432 + o] = lb;
  } else if (blk < 265) {
    int j = (blk - 121) * 256 + t;                // [0,36864)
    int tap = j >> 12, r = j & 4095, ci = r >> 6, co = r & 63;
    float w = w3[j];
    ushortT hb = f2bf(w);
    ushortT lb = f2bf(w - bf2f(hb));
    int o = (tap * 64 + co) * 64 + ci;
    ws[36864 + o] = hb; ws[73728 + o] = lb;
  } else {
    if (t < 32) {
      int n = t;
      #pragma unroll
      for (int k = 0; k < 32; ++k) {
        float w = (k < 9) ? w1[k * 32 + n] : 0.f;
        ushortT hb = f2bf(w);
        ws[W1T_HI + n * 32 + k] = hb;
        ws[W1T_LO + n * 32 + k] = f2bf(w - bf2f(hb));
      }
    }
  }
}

// ---- fully-MFMA conv pipeline: conv1+pool, conv2+pool, conv3 -> s3 frag-major bf16
// smem: s1u [256 rows][40] ushorts @0 (20480B; stage-3 reuses @0 as s3l [49][72])
//       ab0/ab1 [96 rows][40] ushorts @20480/@28160
//       (stage2+: s2u [81][72] overlays @20480)
//       xinb [30][31] ushorts @35840
__global__ __launch_bounds__(256, 4) void conv_fused(
    const float* __restrict__ xg, const float* __restrict__ b1g,
    const float* __restrict__ b2g, const float* __restrict__ b3g,
    const ushortT* __restrict__ wsu, ushortT* __restrict__ s3g)
{
  __shared__ __align__(16) unsigned char smem[37700];
  ushortT* s1u  = (ushortT*)smem;
  ushortT* ab0  = (ushortT*)(smem + 20480);
  ushortT* ab1  = (ushortT*)(smem + 28160);
  ushortT* s2u  = (ushortT*)(smem + 20480);       // overlays ab0/ab1 after stage1
  ushortT* s3l  = (ushortT*)smem;                 // [49][72] after stage2 (s1u dead)
  ushortT* xinb = (ushortT*)(smem + 35840);

  const int t = threadIdx.x, b = blockIdx.x;
  const int lane = t & 63, wid = t >> 6;
  const int ln15 = lane & 15, quad = lane >> 4;

  // phase 0: zero s1u + xinb
  {
    uint4 z = make_uint4(0u, 0u, 0u, 0u);
    uint4* p = (uint4*)s1u;
    for (int i = t; i < 1280; i += 256) p[i] = z;
    unsigned* px = (unsigned*)xinb;
    for (int i = t; i < 465; i += 256) px[i] = 0u;
  }
  __syncthreads();
  // phase 1: load image as bf16
  const float* xb = xg + (long)b * 784;
  for (int i = t; i < 784; i += 256) {
    int y = i / 28, x = i - y * 28;
    xinb[(y + 1) * 31 + (x + 1)] = f2bf(xb[i]);
  }
  __syncthreads();

  // ---- stage 1: conv1 (1->32) via MFMA, im2row chunks (96 rows x stride 40)
  {
    const int ntile = wid & 1, mtg = wid >> 1;
    const int nb = ntile * 16;
    const float bias = b1g[nb + ln15];
    bf16x8 bh1 = *(const bf16x8*)(wsu + W1T_HI + (nb + ln15) * 32 + quad * 8);
    bf16x8 bl1 = *(const bf16x8*)(wsu + W1T_LO + (nb + ln15) * 32 + quad * 8);

    auto build = [&](int c, ushortT* buf) {
      int rows = (c < 8) ? 96 : 16;
      if (t < rows) {
        int gm = c * 96 + t;
        int pp = gm >> 2, q = gm & 3;
        int py = pp / 14, px = pp - py * 14;
        int iy = 2 * py + (q >> 1), ix = 2 * px + (q & 1);
        const ushortT* xr = xinb + iy * 31 + ix;
        unsigned d0 = xr[0]  | ((unsigned)xr[1]  << 16);
        unsigned d1 = xr[2]  | ((unsigned)xr[31] << 16);
        unsigned d2 = xr[32] | ((unsigned)xr[33] << 16);
        unsigned d3 = xr[62] | ((unsigned)xr[63] << 16);
        unsigned d4 = xr[64];
        uint4 z = make_uint4(0u, 0u, 0u, 0u);
        *(uint4*)(buf + t * 40)      = make_uint4(d0, d1, d2, d3);
        *(uint4*)(buf + t * 40 + 8)  = make_uint4(d4, 0u, 0u, 0u);
        *(uint4*)(buf + t * 40 + 16) = z;
        *(uint4*)(buf + t * 40 + 24) = z;
        *(uint4*)(buf + t * 40 + 32) = z;
      }
    };
    auto domfma = [&](int c, ushortT* buf) {
      int cnt = (c < 8) ? 3 : (mtg == 0 ? 1 : 0);
      for (int j = 0; j < cnt; ++j) {
        int ml = (c < 8) ? (mtg * 3 + j) : 0;
        int tile = c * 6 + ml;
        bf16x8 a = *(const bf16x8*)(buf + (ml * 16 + ln15) * 40 + quad * 8);
        f32x4 acc = (f32x4){bias, bias, bias, bias};
        acc = __builtin_amdgcn_mfma_f32_16x16x32_bf16(a, bh1, acc, 0, 0, 0);
        acc = __builtin_amdgcn_mfma_f32_16x16x32_bf16(a, bl1, acc, 0, 0, 0);
        float m = fmaxf(fmaxf(acc[0], acc[1]), fmaxf(acc[2], acc[3]));
        int pp = tile * 4 + quad;
        int py = pp / 14, px = pp - py * 14;
        s1u[((py + 1) * 16 + px + 1) * 40 + nb + ln15] = f2bf(fmaxf(m, 0.f));
      }
    };
    build(0, ab0);
    __syncthreads();
    #pragma unroll 1
    for (int c = 0; c < 9; ++c) {
      ushortT* curb = (c & 1) ? ab1 : ab0;
      domfma(c, curb);
      if (c < 8) build(c + 1, (c & 1) ? ab0 : ab1);
      __syncthreads();
    }
  }
  // zero s2u region (ab buffers dead)
  {
    uint4 z = make_uint4(0u, 0u, 0u, 0u);
    uint4* p = (uint4*)s2u;                        // 5832 ushorts = 729 uint4
    for (int i = t; i < 729; i += 256) p[i] = z;
  }
  __syncthreads();

  // ---- stage 2: conv2 (32->64) MFMA, pool-morton M; prefetched B; pool+relu -> s2u
  {
    const int nth = wid >> 1, mtg = wid & 1;
    const int nmt = mtg ? 6 : 7;
    const int nt0 = nth * 2;
    int abase[7];
    #pragma unroll
    for (int k = 0; k < 7; ++k) {
      int mt = mtg + 2 * k;
      int m = mt * 16 + ln15;
      int pp = m >> 2; if (pp > 48) pp = 48;
      int qq = m & 3;
      int py = pp / 7, px = pp - py * 7;
      int oy = 2 * py + (qq >> 1), ox = 2 * px + (qq & 1);
      abase[k] = (oy * 16 + ox) * 80 + quad * 16;
    }
    const float bia0 = b2g[nt0 * 16 + ln15];
    const float bia1 = b2g[(nt0 + 1) * 16 + ln15];
    f32x4 acc[7][2];
    #pragma unroll
    for (int k = 0; k < 7; ++k) {
      acc[k][0] = (f32x4){bia0, bia0, bia0, bia0};
      acc[k][1] = (f32x4){bia1, bia1, bia1, bia1};
    }
    const char* s1b = (const char*)s1u;
    const ushortT* wbase = wsu + (nt0 * 16 + ln15) * 32 + quad * 8;
    bf16x8 cur[4], nxt[4];
    {
      const ushortT* bp = wbase;
      cur[0] = *(const bf16x8*)bp;
      cur[1] = *(const bf16x8*)(bp + 18432);
      cur[2] = *(const bf16x8*)(bp + 512);
      cur[3] = *(const bf16x8*)(bp + 18432 + 512);
    }
    #pragma unroll 1
    for (int tap = 0; tap < 9; ++tap) {
      {
        int tn = tap < 8 ? tap + 1 : 8;
        const ushortT* bp = wbase + tn * 2048;
        nxt[0] = *(const bf16x8*)bp;
        nxt[1] = *(const bf16x8*)(bp + 18432);
        nxt[2] = *(const bf16x8*)(bp + 512);
        nxt[3] = *(const bf16x8*)(bp + 18432 + 512);
      }
      int ky = tap / 3, kx = tap - (tap / 3) * 3;
      int soff = (ky * 16 + kx) * 80;
      #pragma unroll
      for (int k = 0; k < 7; ++k) {
        if (k < nmt) {
          bf16x8 a = *(const bf16x8*)(s1b + abase[k] + soff);
          acc[k][0] = __builtin_amdgcn_mfma_f32_16x16x32_bf16(a, cur[0], acc[k][0], 0, 0, 0);
          acc[k][0] = __builtin_amdgcn_mfma_f32_16x16x32_bf16(a, cur[1], acc[k][0], 0, 0, 0);
          acc[k][1] = __builtin_amdgcn_mfma_f32_16x16x32_bf16(a, cur[2], acc[k][1], 0, 0, 0);
          acc[k][1] = __builtin_amdgcn_mfma_f32_16x16x32_bf16(a, cur[3], acc[k][1], 0, 0, 0);
        }
      }
      #pragma unroll
      for (int i = 0; i < 4; ++i) cur[i] = nxt[i];
    }
    #pragma unroll
    for (int k = 0; k < 7; ++k) {
      if (k < nmt) {
        int mt = mtg + 2 * k;
        int pp = mt * 4 + quad;
        if (pp < 49) {
          int py = pp / 7, px = pp - py * 7;
          int grow = (py + 1) * 9 + px + 1;
          f32x4 v0 = acc[k][0], v1 = acc[k][1];
          float p0 = fmaxf(fmaxf(v0.x, v0.y), fmaxf(v0.z, v0.w));
          float p1 = fmaxf(fmaxf(v1.x, v1.y), fmaxf(v1.z, v1.w));
          s2u[grow * 72 + nt0 * 16 + ln15]       = f2bf(fmaxf(p0, 0.f));
          s2u[grow * 72 + (nt0 + 1) * 16 + ln15] = f2bf(fmaxf(p1, 0.f));
        }
      }
    }
  }
  __syncthreads();

  // ---- stage 3: conv3 (64->64) MFMA + relu -> s3l LDS, then frag-major global
  {
    int abase2[4];
    #pragma unroll
    for (int mt = 0; mt < 4; ++mt) {
      int op = mt * 16 + ln15; if (op > 48) op = 48;
      int oy = op / 7, ox = op - (op / 7) * 7;
      abase2[mt] = (oy * 9 + ox) * 144 + quad * 16;
    }
    const float bia = b3g[wid * 16 + ln15];
    f32x4 acc3[4];
    #pragma unroll
    for (int mt = 0; mt < 4; ++mt) acc3[mt] = (f32x4){bia, bia, bia, bia};
    const char* s2b = (const char*)s2u;
    const ushortT* w3base = wsu + 36864 + (wid * 16 + ln15) * 64 + quad * 8;
    bf16x8 cur[4], nxt[4];
    {
      const ushortT* bp = w3base;
      cur[0] = *(const bf16x8*)bp;
      cur[1] = *(const bf16x8*)(bp + 36864);
      cur[2] = *(const bf16x8*)(bp + 32);
      cur[3] = *(const bf16x8*)(bp + 36864 + 32);
    }
    #pragma unroll 1
    for (int tap = 0; tap < 9; ++tap) {
      {
        int tn = tap < 8 ? tap + 1 : 8;
        const ushortT* bp = w3base + tn * 4096;
        nxt[0] = *(const bf16x8*)bp;
        nxt[1] = *(const bf16x8*)(bp + 36864);
        nxt[2] = *(const bf16x8*)(bp + 32);
        nxt[3] = *(const bf16x8*)(bp + 36864 + 32);
      }
      int ky = tap / 3, kx = tap - (tap / 3) * 3;
      int soff = (ky * 9 + kx) * 144;
      #pragma unroll
      for (int kc = 0; kc < 2; ++kc) {
        #pragma unroll
        for (int mt = 0; mt < 4; ++mt) {
          bf16x8 a = *(const bf16x8*)(s2b + abase2[mt] + soff + kc * 64);
          acc3[mt] = __builtin_amdgcn_mfma_f32_16x16x32_bf16(a, cur[kc * 2],     acc3[mt], 0, 0, 0);
          acc3[mt] = __builtin_amdgcn_mfma_f32_16x16x32_bf16(a, cur[kc * 2 + 1], acc3[mt], 0, 0, 0);
        }
      }
      #pragma unroll
      for (int i = 0; i < 4; ++i) cur[i] = nxt[i];
    }
    // write to s3l [op][72] (s1u region dead; stage-2 reads done via barrier above)
    #pragma unroll
    for (int mt = 0; mt < 4; ++mt)
      #pragma unroll
      for (int r = 0; r < 4; ++r) {
        int op = mt * 16 + quad * 4 + r;
        if (op < 49) s3l[op * 72 + wid * 16 + ln15] = f2bf(fmaxf(acc3[mt][r], 0.f));
      }
  }
  __syncthreads();
  // cooperative frag-major store: chunk i -> (kk=i>>2, qf=i&3), 16 B each
  {
    const long gbase = (long)(b >> 4) * 98 * 512 + (long)(b & 15) * 8;
    for (int i = t; i < 392; i += 256) {
      int op = i >> 3, c8 = i & 7;
      uint4 v = *(const uint4*)(s3l + op * 72 + c8 * 8);
      int kk = i >> 2, qf = i & 3;
      *(uint4*)(s3g + gbase + (long)kk * 512 + qf * 128) = v;
    }
  }
}

// ---- dense1 (MFMA, 4 n-tiles x 4 K-quarters, frag-major coalesced) + dense2 + softmax
__global__ __launch_bounds__(1024) void dense_mfma(
    const ushortT* __restrict__ ws, const float* __restrict__ bd1g,
    const float* __restrict__ wd2g, const float* __restrict__ bd2g,
    float* __restrict__ out)
{
  __shared__ float part[16 * 256];   // [(kq*4+nt)][im*16+c15]
  __shared__ float hv[16 * 64];
  __shared__ float lgle[16 * 24];
  const int t = threadIdx.x;
  const int lane = t & 63, wid = t >> 6;
  const int ln15 = lane & 15, quad = lane >> 4;
  const int nt = wid & 3, kq = wid >> 2;
  const int g = blockIdx.x, m0 = g * 16;
  const int ks = kq * 24 + (kq < 2 ? kq : 2);
  const int ke = ks + (kq < 2 ? 25 : 24);

  const ushortT* a_p = ws + S3F_OFF + ((long)g * 98 + ks) * 512 + lane * 8;
  const ushortT* h_p = ws + WD1F_HI + ((long)(nt * 98 + ks)) * 512 + lane * 8;
  const ushortT* l_p = ws + WD1F_LO + ((long)(nt * 98 + ks)) * 512 + lane * 8;

  bf16x8 a  = *(const bf16x8*)a_p;
  bf16x8 wh = *(const bf16x8*)h_p;
  bf16x8 wl = *(const bf16x8*)l_p;
  f32x4 ac0 = (f32x4){0.f, 0.f, 0.f, 0.f};
  f32x4 ac1 = (f32x4){0.f, 0.f, 0.f, 0.f};
  const int n = ke - ks;
  #pragma unroll 2
  for (int i = 1; i < n; ++i) {
    bf16x8 na = *(const bf16x8*)(a_p + i * 512);
    bf16x8 nh = *(const bf16x8*)(h_p + i * 512);
    bf16x8 nl = *(const bf16x8*)(l_p + i * 512);
    ac0 = __builtin_amdgcn_mfma_f32_16x16x32_bf16(a, wh, ac0, 0, 0, 0);
    ac1 = __builtin_amdgcn_mfma_f32_16x16x32_bf16(a, wl, ac1, 0, 0, 0);
    a = na; wh = nh; wl = nl;
  }
  ac0 = __builtin_amdgcn_mfma_f32_16x16x32_bf16(a, wh, ac0, 0, 0, 0);
  ac1 = __builtin_amdgcn_mfma_f32_16x16x32_bf16(a, wl, ac1, 0, 0, 0);
  float* dst = part + (kq * 4 + nt) * 256;
  #pragma unroll
  for (int r = 0; r < 4; ++r)
    dst[(quad * 4 + r) * 16 + ln15] = ac0[r] + ac1[r];
  __syncthreads();

  {
    const int im = t >> 6, ch = t & 63;
    const int ntc = ch >> 4, c15 = ch & 15;
    float v = bd1g[ch];
    #pragma unroll
    for (int k2 = 0; k2 < 4; ++k2)
      v += part[(k2 * 4 + ntc) * 256 + im * 16 + c15];
    hv[im * 64 + ch] = fmaxf(v, 0.f);
  }
  __syncthreads();

  float* lg = lgle;
  float* le = lgle + 192;
  if (t < 160) {
    int im = t / 10, c = t - im * 10;
    float a2 = bd2g[c];
    #pragma unroll
    for (int k = 0; k < 64; ++k) a2 = fmaf(hv[im * 64 + k], wd2g[k * 10 + c], a2);
    lg[im * 12 + c] = a2;
  }
  __syncthreads();
  if (t < 160) {
    int im = t / 10, c = t - im * 10;
    float m = lg[im * 12];
    #pragma unroll
    for (int i = 1; i < 10; ++i) m = fmaxf(m, lg[im * 12 + i]);
    le[im * 12 + c] = expf(lg[im * 12 + c] - m);
  }
  __syncthreads();
  if (t < 160) {
    int im = t / 10, c = t - im * 10;
    float s = 0.f;
    #pragma unroll
    for (int i = 0; i < 10; ++i) s += le[im * 12 + i];
    out[(long)(m0 + im) * 10 + c] = le[im * 12 + c] / s;
  }
}

extern "C" void kernel_launch(void* const* d_in, const int* in_sizes, int n_in,
                              void* d_out, int out_size, void* d_ws, size_t ws_size,
                              hipStream_t stream) {
  (void)in_sizes; (void)n_in; (void)out_size; (void)ws_size;
  const float* x   = (const float*)d_in[0];
  const float* w1  = (const float*)d_in[1];
  const float* b1  = (const float*)d_in[2];
  const float* w2  = (const float*)d_in[3];
  const float* b2  = (const float*)d_in[4];
  const float* w3  = (const float*)d_in[5];
  const float* b3  = (const float*)d_in[6];
  const float* wd1 = (const float*)d_in[7];
  const float* bd1 = (const float*)d_in[8];
  const float* wd2 = (const float*)d_in[9];
  const float* bd2 = (const float*)d_in[10];
  float* out = (float*)d_out;
  ushortT* wsu = (ushortT*)d_ws;
  ushortT* s3g = wsu + S3F_OFF;

  hipLaunchKernelGGL(prep_w, dim3(266), dim3(256), 0, stream, w1, w2, w3, wd1, wsu);
  hipLaunchKernelGGL(conv_fused, dim3(NBATCH), dim3(256), 0, stream,
                     x, b1, b2, b3, wsu, s3g);
  hipLaunchKernelGGL(dense_mfma, dim3(NBATCH / 16), dim3(1024), 0, stream,
                     wsu, bd1, wd2, bd2, out);
}